// Round 14
// baseline (1489.829 us; speedup 1.0000x reference)
//
#include <hip/hip_runtime.h>

#define BB 16
#define TY 255
#define ENC 512
#define EMBD 256
#define DEC 512
#define VV 32000
#define LL 256          // TY+1
#define M4 4096         // B*L
#define GG 2048         // 4*DEC
#define SENT 0x7FC0     // bf16 NaN; |h|<1 can never round to this

typedef unsigned short u16;
typedef __attribute__((ext_vector_type(8))) short short8;
typedef __attribute__((ext_vector_type(4))) float f32x4;
typedef __attribute__((ext_vector_type(4))) unsigned short u16x4;

__device__ __forceinline__ u16 f2bf(float f) {
  unsigned u = __float_as_uint(f);
  u += 0x7fff + ((u >> 16) & 1);
  return (u16)(u >> 16);
}
__device__ __forceinline__ f32x4 mfma16(short8 a, short8 b, f32x4 c) {
  return __builtin_amdgcn_mfma_f32_16x16x32_bf16(a, b, c, 0, 0, 0);
}
__device__ __forceinline__ float sigmoidf_(float x) { return 1.f / (1.f + expf(-x)); }

// ---- device-scope (sc1: coherent at Infinity Cache) store — proven rounds 3-9 ----
__device__ __forceinline__ void st_b32_dev(int* a, int v) {
  asm volatile("global_store_dword %0, %1, off sc1" :: "v"(a), "v"(v) : "memory");
}
// ---- async global->LDS, 16B per lane (wave-uniform LDS base + lane*16) ----
__device__ __forceinline__ void gload_lds16(const u16* g, u16* l) {
  __builtin_amdgcn_global_load_lds(
      (const __attribute__((address_space(1))) void*)g,
      (__attribute__((address_space(3))) void*)l, 16, 0, 0);
}

// ---------------- 64² bf16 MFMA GEMM (kept for the NN mix GEMM) ----------------
template<bool BT, bool OBF, bool DOTANH, bool BIAS>
__global__ __launch_bounds__(256) void gemm_kernel(
    const u16* __restrict__ A, const u16* __restrict__ Bm, void* __restrict__ Cv,
    const float* __restrict__ bias,
    int K, int lda, int ldb, int ldc,
    long a_bs, long b_bs, long c_bs)
{
  __shared__ u16 As[64][72];
  __shared__ u16 Bs[64][72];
  const int tid = threadIdx.x;
  const long m0 = (long)blockIdx.y * 64, n0 = (long)blockIdx.x * 64;
  const int z = blockIdx.z;
  const u16* Ab = A + (long)z * a_bs;
  const u16* Bb = Bm + (long)z * b_bs;
  const int lane = tid & 63, w = tid >> 6;
  const int wm = w >> 1, wn = w & 1;
  f32x4 acc[2][2] = {};
  for (int k0 = 0; k0 < K; k0 += 64) {
#pragma unroll
    for (int i = 0; i < 2; i++) {
      int c = tid + 256 * i;
      int r = c >> 3, kk = (c & 7) << 3;
      *(short8*)&As[r][kk] = *(const short8*)&Ab[(m0 + r) * (long)lda + k0 + kk];
    }
    if (BT) {
#pragma unroll
      for (int i = 0; i < 2; i++) {
        int c = tid + 256 * i;
        int r = c >> 3, kk = (c & 7) << 3;
        *(short8*)&Bs[r][kk] = *(const short8*)&Bb[(n0 + r) * (long)ldb + k0 + kk];
      }
    } else {
#pragma unroll
      for (int i = 0; i < 2; i++) {
        int c = tid + 256 * i;
        int kk = c >> 3, nn = (c & 7) << 3;
        const u16* s = &Bb[(long)(k0 + kk) * ldb + n0 + nn];
#pragma unroll
        for (int j = 0; j < 8; j++) Bs[nn + j][kk] = s[j];
      }
    }
    __syncthreads();
#pragma unroll
    for (int kf = 0; kf < 2; kf++) {
      const int ko = kf * 32 + (lane >> 4) * 8;
      short8 a0 = *(const short8*)&As[wm * 32 + (lane & 15)][ko];
      short8 a1 = *(const short8*)&As[wm * 32 + 16 + (lane & 15)][ko];
      short8 b0 = *(const short8*)&Bs[wn * 32 + (lane & 15)][ko];
      short8 b1 = *(const short8*)&Bs[wn * 32 + 16 + (lane & 15)][ko];
      acc[0][0] = mfma16(a0, b0, acc[0][0]);
      acc[0][1] = mfma16(a0, b1, acc[0][1]);
      acc[1][0] = mfma16(a1, b0, acc[1][0]);
      acc[1][1] = mfma16(a1, b1, acc[1][1]);
    }
    __syncthreads();
  }
#pragma unroll
  for (int m = 0; m < 2; m++)
#pragma unroll
    for (int n = 0; n < 2; n++) {
#pragma unroll
      for (int r = 0; r < 4; r++) {
        long row = m0 + wm * 32 + m * 16 + (lane >> 4) * 4 + r;
        long col = n0 + wn * 32 + n * 16 + (lane & 15);
        float v = acc[m][n][r];
        if (BIAS) v += bias[col];
        if (DOTANH) v = tanhf(v);
        if (OBF) ((u16*)Cv)[(long)z * c_bs + row * ldc + col] = f2bf(v);
        else ((float*)Cv)[(long)z * c_bs + row * ldc + col] = v;
      }
    }
}

// ---------------- 128² bf16 MFMA GEMM, BT only, global_load_lds staging (m97 structure) ---------
// SWZ variant (fc2 only): flat 8000-block grid, bijective XCD chunking, B-panel-major
// ordering — consecutive blocks within an XCD chunk share the 128KB B-panel (L2 reuse
// x32), and the whole 4MB A matrix stays L2/L3-hot. nwg=8000, 1000/XCD, 32 M-tiles.
template<bool OBF, bool DOTANH, bool BIAS, bool SWZ>
__global__ __launch_bounds__(256) void gemm128_kernel(
    const u16* __restrict__ A, const u16* __restrict__ Bm, void* __restrict__ Cv,
    const float* __restrict__ bias,
    int K, int lda, int ldb, int ldc,
    long a_bs, long b_bs, long c_bs)
{
  __shared__ u16 As[128 * 64];   // linear [row][64], row stride 64 u16
  __shared__ u16 Bs[128 * 64];
  const int tid = threadIdx.x;
  long m0, n0;
  if (SWZ) {
    int bid = blockIdx.x;
    int sb = (bid & 7) * 1000 + (bid >> 3);   // XCD chunk (8000 % 8 == 0 -> bijective)
    m0 = (long)(sb % 32) * 128;               // M-tile: fast index (shares B-panel)
    n0 = (long)(sb / 32) * 128;               // N-tile: slow index
  } else {
    m0 = (long)blockIdx.y * 128;
    n0 = (long)blockIdx.x * 128;
  }
  const int z = SWZ ? 0 : blockIdx.z;
  const u16* Ab = A + (long)z * a_bs;
  const u16* Bb = Bm + (long)z * b_bs;
  const int lane = tid & 63, w = tid >> 6;
  const int wm = w >> 1, wn = w & 1;
  const int rr = tid >> 3, kk = (tid & 7) << 3;   // per-issue i: row = i*32 + rr
  f32x4 acc[4][4] = {};
  for (int k0 = 0; k0 < K; k0 += 64) {
#pragma unroll
    for (int i = 0; i < 4; i++) {
      gload_lds16(&Ab[(m0 + i * 32 + rr) * (long)lda + k0 + kk],
                  As + (i * 256 + (w << 6)) * 8);
      gload_lds16(&Bb[(n0 + i * 32 + rr) * (long)ldb + k0 + kk],
                  Bs + (i * 256 + (w << 6)) * 8);
    }
    __syncthreads();   // drains vmcnt(0): LDS tiles complete
#pragma unroll
    for (int kf = 0; kf < 2; kf++) {
      const int ko = kf * 32 + (lane >> 4) * 8;
      short8 a[4], b[4];
#pragma unroll
      for (int mi = 0; mi < 4; mi++)
        a[mi] = *(const short8*)&As[(wm * 64 + mi * 16 + (lane & 15)) * 64 + ko];
#pragma unroll
      for (int ni = 0; ni < 4; ni++)
        b[ni] = *(const short8*)&Bs[(wn * 64 + ni * 16 + (lane & 15)) * 64 + ko];
#pragma unroll
      for (int mi = 0; mi < 4; mi++)
#pragma unroll
        for (int ni = 0; ni < 4; ni++)
          acc[mi][ni] = mfma16(a[mi], b[ni], acc[mi][ni]);
    }
    __syncthreads();
  }
#pragma unroll
  for (int mi = 0; mi < 4; mi++)
#pragma unroll
    for (int ni = 0; ni < 4; ni++) {
#pragma unroll
      for (int r = 0; r < 4; r++) {
        long row = m0 + wm * 64 + mi * 16 + (lane >> 4) * 4 + r;
        long col = n0 + wn * 64 + ni * 16 + (lane & 15);
        float v = acc[mi][ni][r];
        if (BIAS) v += bias[col];
        if (DOTANH) v = tanhf(v);
        if (OBF) ((u16*)Cv)[(long)z * c_bs + row * ldc + col] = f2bf(v);
        else ((float*)Cv)[(long)z * c_bs + row * ldc + col] = v;
      }
    }
}

// ---------------- sentinel prefill (standalone, for LSTM2's refill) ----------------
__global__ void sentinel_kernel(u16* __restrict__ p) {
  long i = ((long)blockIdx.x * 256 + threadIdx.x) * 8;
  short v = (i < 8192) ? (short)0 : (short)SENT;
  short8 s = {v, v, v, v, v, v, v, v};
  *(short8*)&p[i] = s;
}

// ---------------- persistent LSTM: round-9 EXACT (proven 528 µs) ----------------
// 32 blocks x 256 threads; sentinel-tagged staged handoff; simple 4-chunk poll;
// coalesced publish/hout/xg (thread (b=tid>>4, jl=tid&15) owns (batch b, unit nb*16+jl)).
// MODE 0: write h into cat[:, 512:1024]. MODE 1: write h into h2 (ld 512).
template<int MODE>
__global__ __launch_bounds__(256) void lstm_kernel(
    const float* __restrict__ xw,   // [4096][2048] permuted, biases folded in
    const u16* __restrict__ Whh,    // [2048][512] permuted rows, bf16
    u16* __restrict__ Hseq,         // [257][16][512] sentinel-prefilled
    u16* __restrict__ hout)
{
  const int nb = blockIdx.x;
  const int tid = threadIdx.x;
  const int lane = tid & 63, w = tid >> 6;
  __shared__ u16 hs[16][520];       // staged h_{t-1}; +8 u16 pad keeps rows 16B-aligned
  __shared__ float gbuf[16][64];
  const int ncol0 = nb * 64 + w * 16;
  short8 bfrag[16];
  {
    const u16* wr = Whh + (long)(ncol0 + (lane & 15)) * 512 + ((lane >> 4) * 8);
#pragma unroll
    for (int kf = 0; kf < 16; kf++) bfrag[kf] = *(const short8*)&wr[kf * 32];
  }
  const int b = tid >> 4, jl = tid & 15;
  const int jglob = nb * 16 + jl;
  int cc[4];                        // 16B-chunk ids, rotated per block
#pragma unroll
  for (int i = 0; i < 4; i++) cc[i] = (tid + i * 256 + nb * 32) & 1023;
  float c = 0.f;
  float4 xg = *(const float4*)&xw[((long)b * LL) * GG + nb * 64 + jl * 4];
  for (int t = 0; t < LL; t++) {
    // ---- poll-stage h_{t-1}: re-issue own 4 chunks until sentinel-free ----
    const u16* Hin = Hseq + (long)t * 8192;
    short8 sv[4];
    int bad;
    do {
#pragma unroll
      for (int i = 0; i < 4; i++)
        asm volatile("global_load_dwordx4 %0, %1, off sc1"
                     : "=v"(sv[i]) : "v"(Hin + (cc[i] >> 6) * 512 + (cc[i] & 63) * 8));
      asm volatile("s_waitcnt vmcnt(0)" ::: "memory");
      __builtin_amdgcn_sched_barrier(0);   // rule #18: nothing crosses the waitcnt
      bad = 0;
#pragma unroll
      for (int i = 0; i < 4; i++) {
        const int* dv = (const int*)&sv[i];
#pragma unroll
        for (int d = 0; d < 4; d++) bad |= ((dv[d] & 0xFFFF) == SENT);
      }
    } while (__any(bad != 0));
    __builtin_amdgcn_sched_barrier(0);
#pragma unroll
    for (int i = 0; i < 4; i++)
      *(short8*)&hs[cc[i] >> 6][(cc[i] & 63) * 8] = sv[i];
    __syncthreads();                 // barrier 1: hs staged
    // ---- MFMA from LDS fragments ----
    f32x4 acc0 = {}, acc1 = {};
#pragma unroll
    for (int kf = 0; kf < 8; kf++) {
      short8 a0 = *(const short8*)&hs[lane & 15][(lane >> 4) * 8 + (2 * kf) * 32];
      short8 a1 = *(const short8*)&hs[lane & 15][(lane >> 4) * 8 + (2 * kf + 1) * 32];
      acc0 = mfma16(a0, bfrag[2 * kf], acc0);
      acc1 = mfma16(a1, bfrag[2 * kf + 1], acc1);
    }
    f32x4 acc = acc0 + acc1;
#pragma unroll
    for (int r = 0; r < 4; r++)
      gbuf[(lane >> 4) * 4 + r][w * 16 + (lane & 15)] = acc[r];
    __syncthreads();                 // barrier 2: gbuf ready (also fences hs reads)
    float gi = sigmoidf_(gbuf[b][jl * 4 + 0] + xg.x);
    float gf = sigmoidf_(gbuf[b][jl * 4 + 1] + xg.y);
    float gg = tanhf(gbuf[b][jl * 4 + 2] + xg.z);
    float go = sigmoidf_(gbuf[b][jl * 4 + 3] + xg.w);
    c = gf * c + gi * gg;
    float h = go * tanhf(c);
    u16 hb = f2bf(h);
    // ---- publish h_t: pack pairs, one atomic dword sc1 store per even-jl thread ----
    unsigned hi16 = (unsigned)__shfl_down((int)(unsigned)hb, 1);
    if ((jl & 1) == 0) {
      int pk = (int)((unsigned)hb | (hi16 << 16));
      st_b32_dev((int*)&Hseq[((long)t + 1) * 8192 + b * 512 + jglob], pk);
    }
    if (MODE == 0) hout[((long)b * LL + t) * 1024 + 512 + jglob] = hb;
    else           hout[((long)b * LL + t) * 512 + jglob] = hb;
    // next step's gate slice (plain load; retired by the next poll's vmcnt(0))
    if (t + 1 < LL)
      xg = *(const float4*)&xw[((long)b * LL + (t + 1)) * GG + nb * 64 + jl * 4];
  }
}

// ---------------- fused prep: all independent elementwise prework in ONE launch ----------------
__global__ __launch_bounds__(256) void prep_kernel(
    const float* __restrict__ l1_Wih, const float* __restrict__ l1_Whh,
    const float* __restrict__ dc_Wih, const float* __restrict__ dc_Whh,
    const float* __restrict__ l1_bih, const float* __restrict__ l1_bhh,
    const float* __restrict__ dc_bih, const float* __restrict__ dc_bhh,
    const float* __restrict__ Wout,  const float* __restrict__ fc2_w,
    const int*   __restrict__ y,     const float* __restrict__ emb,
    const float* __restrict__ x,     const float* __restrict__ fc1_w,
    const float* __restrict__ fc1_b,
    u16* wih1, u16* whh1, u16* wih2, u16* whh2,
    float* b1p, float* b2p, u16* woutb, u16* fc2wb,
    u16* seqb, u16* Hseq, float* feat)
{
  const int bid = blockIdx.x;
  const int tid = threadIdx.x;
  if (bid < 8192) {                       // 4 weight permute+converts
    int grp = bid >> 11, n = bid & 2047;
    const float* s; u16* d; int ldk;
    if (grp == 0)      { s = l1_Wih; d = wih1; ldk = EMBD; }
    else if (grp == 1) { s = l1_Whh; d = whh1; ldk = DEC; }
    else if (grp == 2) { s = dc_Wih; d = wih2; ldk = DEC; }
    else               { s = dc_Whh; d = whh2; ldk = DEC; }
    int r = (n & 3) * DEC + (n >> 2);
    for (int k = tid; k < ldk; k += 256)
      d[(long)n * ldk + k] = f2bf(s[(long)r * ldk + k]);
  } else if (bid < 8208) {                // bias folds
    int idx = bid - 8192;
    int n = (idx & 7) * 256 + tid;
    int r = (n & 3) * DEC + (n >> 2);
    if (idx < 8) b1p[n] = l1_bih[r] + l1_bhh[r];
    else         b2p[n] = dc_bih[r] + dc_bhh[r];
  } else if (bid < 8720) {                // woutb cvt
    long i = ((long)(bid - 8208) * 256 + tid) * 4;
    float4 v = *(const float4*)&Wout[i];
    u16x4 o = {f2bf(v.x), f2bf(v.y), f2bf(v.z), f2bf(v.w)};
    *(u16x4*)&woutb[i] = o;
  } else if (bid < 24720) {               // fc2wb cvt
    long i = ((long)(bid - 8720) * 256 + tid) * 4;
    float4 v = *(const float4*)&fc2_w[i];
    u16x4 o = {f2bf(v.x), f2bf(v.y), f2bf(v.z), f2bf(v.w)};
    *(u16x4*)&fc2wb[i] = o;
  } else if (bid < 28800) {               // embed
    int idx = bid - 24720;
    int t = idx % TY, bb = idx / TY;
    int tok = y[bb * TY + t];
    seqb[((long)bb * LL + 1 + t) * EMBD + tid] = f2bf(emb[(long)tok * EMBD + tid]);
  } else if (bid < 29828) {               // sentinel prefill
    long i = ((long)(bid - 28800) * 256 + tid) * 8;
    short v = (i < 8192) ? (short)0 : (short)SENT;
    short8 s = {v, v, v, v, v, v, v, v};
    *(short8*)&Hseq[i] = s;
  } else {                                // fc1
    __shared__ float xs[ENC];
    int bb = bid - 29828;
    for (int k = tid; k < ENC; k += 256) xs[k] = x[bb * ENC + k];
    __syncthreads();
    float s = fc1_b[tid];
    const float* wr = fc1_w + (long)tid * ENC;
    for (int k = 0; k < ENC; k += 4) {
      float4 wv = *(const float4*)&wr[k];
      s += xs[k] * wv.x + xs[k + 1] * wv.y + xs[k + 2] * wv.z + xs[k + 3] * wv.w;
    }
    feat[bb * EMBD + tid] = s;
  }
}

__global__ void bn_embed0_kernel(const float* __restrict__ feat, const float* __restrict__ g,
                                 const float* __restrict__ bb, u16* __restrict__ seq) {
  int j = threadIdx.x;  // 256 features, 1 block
  float mu = 0.f, m2 = 0.f;
  for (int i = 0; i < BB; i++) { float v = feat[i * EMBD + j]; mu += v; m2 += v * v; }
  mu *= (1.f / BB);
  float var = m2 * (1.f / BB) - mu * mu;
  float sc = g[j] * rsqrtf(var + 1e-5f);
  float sh = bb[j];
  for (int i = 0; i < BB; i++) {
    float v = (feat[i * EMBD + j] - mu) * sc + sh;
    seq[((long)i * LL) * EMBD + j] = f2bf(v);
  }
}

__global__ __launch_bounds__(256) void softmax_kernel(const float* __restrict__ sc,
                                                      u16* __restrict__ wsm) {
  int row = blockIdx.x;
  int q = row & (LL - 1);
  int k = threadIdx.x;
  __shared__ float red[8];
  float v = (k <= q) ? sc[(long)row * LL + k] : -3.4e38f;
  float m = v;
#pragma unroll
  for (int o = 32; o > 0; o >>= 1) m = fmaxf(m, __shfl_xor(m, o));
  if ((k & 63) == 0) red[k >> 6] = m;
  __syncthreads();
  m = fmaxf(fmaxf(red[0], red[1]), fmaxf(red[2], red[3]));
  float e = (k <= q) ? expf(v - m) : 0.f;
  float s = e;
#pragma unroll
  for (int o = 32; o > 0; o >>= 1) s += __shfl_xor(s, o);
  if ((k & 63) == 0) red[4 + (k >> 6)] = s;
  __syncthreads();
  s = red[4] + red[5] + red[6] + red[7];
  wsm[(long)row * LL + k] = f2bf(e / s);
}

extern "C" void kernel_launch(void* const* d_in, const int* in_sizes, int n_in,
                              void* d_out, int out_size, void* d_ws, size_t ws_size,
                              hipStream_t stream) {
  const float* x      = (const float*)d_in[0];
  const int*   y      = (const int*)d_in[1];
  const float* fc1_w  = (const float*)d_in[2];
  const float* fc1_b  = (const float*)d_in[3];
  const float* bn_g   = (const float*)d_in[4];
  const float* bn_b   = (const float*)d_in[5];
  const float* emb    = (const float*)d_in[6];
  const float* l1_Wih = (const float*)d_in[7];
  const float* l1_Whh = (const float*)d_in[8];
  const float* l1_bih = (const float*)d_in[9];
  const float* l1_bhh = (const float*)d_in[10];
  const float* Wout   = (const float*)d_in[11];
  const float* dc_Wih = (const float*)d_in[12];
  const float* dc_Whh = (const float*)d_in[13];
  const float* dc_bih = (const float*)d_in[14];
  const float* dc_bhh = (const float*)d_in[15];
  const float* fc2_w  = (const float*)d_in[16];
  const float* fc2_b  = (const float*)d_in[17];
  float* out = (float*)d_out;

  char* ws = (char*)d_ws;
  float* xw     = (float*)(ws + 0);          // 4096*2048 f32 (reused for both LSTMs)
  u16*   seqb   = (u16*)(ws + 33554432);     // 4096*256 bf16
  u16*   cat    = (u16*)(ws + 35651584);     // 4096*1024 bf16  [mix | h1]
  float* scores = (float*)(ws + 44040192);   // 16*256*256 f32
  u16*   Hseq   = (u16*)(ws + 44040192);     // 257*16*512 bf16 — aliases scores (disjoint lifetime)
  u16*   wsm    = (u16*)(ws + 48234496);     // 16*256*256 bf16 (head overlaps Hseq tail, disjoint lifetime)
  u16*   attnb  = (u16*)(ws + 50331648);     // 4096*512 bf16
  u16*   h2b    = (u16*)(ws + 54525952);     // 4096*512 bf16
  u16*   wih1   = (u16*)(ws + 58720256);     // 2048*256
  u16*   whh1   = (u16*)(ws + 59768832);     // 2048*512
  u16*   wih2   = (u16*)(ws + 61865984);     // 2048*512
  u16*   whh2   = (u16*)(ws + 63963136);     // 2048*512
  u16*   woutb  = (u16*)(ws + 66060288);     // 512*1024
  u16*   fc2wb  = (u16*)(ws + 67108864);     // 32000*512
  float* b1p    = (float*)(ws + 99876864);   // 2048
  float* b2p    = (float*)(ws + 99885056);   // 2048
  float* feat   = (float*)(ws + 99893248);   // 16*256

  // ---- fused prep: weights/biases/embed/sentinel/fc1 in one launch ----
  prep_kernel<<<29844, 256, 0, stream>>>(
      l1_Wih, l1_Whh, dc_Wih, dc_Whh, l1_bih, l1_bhh, dc_bih, dc_bhh,
      Wout, fc2_w, y, emb, x, fc1_w, fc1_b,
      wih1, whh1, wih2, whh2, b1p, b2p, woutb, fc2wb, seqb, Hseq, feat);
  bn_embed0_kernel<<<1, 256, 0, stream>>>(feat, bn_g, bn_b, seqb);

  // xw1 = seq @ l1_Wih^T + (bih+bhh)   M=4096 N=2048 K=256
  gemm128_kernel<false, false, true, false><<<dim3(GG / 128, M4 / 128, 1), 256, 0, stream>>>(
      seqb, wih1, xw, b1p, EMBD, EMBD, EMBD, GG, 0, 0, 0);
  // LSTM1 -> h1 into cat[:,512:1024]
  lstm_kernel<0><<<32, 256, 0, stream>>>(xw, whh1, Hseq, cat);
  // scores[b] = h1 @ h1^T   (per batch) — overwrites Hseq (dead)
  gemm128_kernel<false, false, false, false><<<dim3(LL / 128, LL / 128, BB), 256, 0, stream>>>(
      cat + 512, cat + 512, scores, nullptr, DEC, 1024, 1024, LL,
      (long)LL * 1024, (long)LL * 1024, (long)LL * LL);
  softmax_kernel<<<M4, 256, 0, stream>>>(scores, wsm);
  // mix[b] = wsm @ h1 (NN) -> cat[:,0:512] bf16   (64² kernel: NN path)
  gemm_kernel<false, true, false, false><<<dim3(DEC / 64, LL / 64, BB), 256, 0, stream>>>(
      wsm, cat + 512, cat, nullptr, LL, LL, 1024, 1024,
      (long)LL * LL, (long)LL * 1024, (long)LL * 1024);
  // attn = tanh(cat @ Wout^T)   M=4096 N=512 K=1024
  gemm128_kernel<true, true, false, false><<<dim3(DEC / 128, M4 / 128, 1), 256, 0, stream>>>(
      cat, woutb, attnb, nullptr, 1024, 1024, 1024, DEC, 0, 0, 0);
  // xw2 = attn @ dc_Wih^T + (bih+bhh)   M=4096 N=2048 K=512
  gemm128_kernel<false, false, true, false><<<dim3(GG / 128, M4 / 128, 1), 256, 0, stream>>>(
      attnb, wih2, xw, b2p, DEC, DEC, DEC, GG, 0, 0, 0);
  // LSTM2 -> h2 (scores/wsm head dead again -> re-sentinel Hseq)
  sentinel_kernel<<<1028, 256, 0, stream>>>(Hseq);
  lstm_kernel<1><<<32, 256, 0, stream>>>(xw, whh2, Hseq, h2b);
  // out = h2 @ fc2_w^T + fc2_b   M=4096 N=32000 K=512
  // B-panel-major + XCD-chunked ordering (SWZ): 8000 flat blocks, 32 M-tiles x 250 N-tiles
  gemm128_kernel<false, false, true, true><<<dim3(8000, 1, 1), 256, 0, stream>>>(
      h2b, fc2wb, out, fc2_b, DEC, DEC, DEC, VV, 0, 0, 0);
}

// Round 15
// 1445.201 us; speedup vs baseline: 1.0309x; 1.0309x over previous
//
#include <hip/hip_runtime.h>

#define BB 16
#define TY 255
#define ENC 512
#define EMBD 256
#define DEC 512
#define VV 32000
#define LL 256          // TY+1
#define M4 4096         // B*L
#define GG 2048         // 4*DEC
#define SENT 0x7FC0     // bf16 NaN; |h|<1 can never round to this

typedef unsigned short u16;
typedef __attribute__((ext_vector_type(8))) short short8;
typedef __attribute__((ext_vector_type(4))) float f32x4;
typedef __attribute__((ext_vector_type(4))) unsigned short u16x4;

__device__ __forceinline__ u16 f2bf(float f) {
  unsigned u = __float_as_uint(f);
  u += 0x7fff + ((u >> 16) & 1);
  return (u16)(u >> 16);
}
__device__ __forceinline__ f32x4 mfma16(short8 a, short8 b, f32x4 c) {
  return __builtin_amdgcn_mfma_f32_16x16x32_bf16(a, b, c, 0, 0, 0);
}
__device__ __forceinline__ float sigmoidf_(float x) { return 1.f / (1.f + expf(-x)); }

// ---- device-scope (sc1: coherent at Infinity Cache) store — proven rounds 3-9 ----
__device__ __forceinline__ void st_b32_dev(int* a, int v) {
  asm volatile("global_store_dword %0, %1, off sc1" :: "v"(a), "v"(v) : "memory");
}
// ---- async global->LDS, 16B per lane (wave-uniform LDS base + lane*16) ----
__device__ __forceinline__ void gload_lds16(const u16* g, u16* l) {
  __builtin_amdgcn_global_load_lds(
      (const __attribute__((address_space(1))) void*)g,
      (__attribute__((address_space(3))) void*)l, 16, 0, 0);
}

// ---------------- 64² bf16 MFMA GEMM (kept for the NN mix GEMM) ----------------
template<bool BT, bool OBF, bool DOTANH, bool BIAS>
__global__ __launch_bounds__(256) void gemm_kernel(
    const u16* __restrict__ A, const u16* __restrict__ Bm, void* __restrict__ Cv,
    const float* __restrict__ bias,
    int K, int lda, int ldb, int ldc,
    long a_bs, long b_bs, long c_bs)
{
  __shared__ u16 As[64][72];
  __shared__ u16 Bs[64][72];
  const int tid = threadIdx.x;
  const long m0 = (long)blockIdx.y * 64, n0 = (long)blockIdx.x * 64;
  const int z = blockIdx.z;
  const u16* Ab = A + (long)z * a_bs;
  const u16* Bb = Bm + (long)z * b_bs;
  const int lane = tid & 63, w = tid >> 6;
  const int wm = w >> 1, wn = w & 1;
  f32x4 acc[2][2] = {};
  for (int k0 = 0; k0 < K; k0 += 64) {
#pragma unroll
    for (int i = 0; i < 2; i++) {
      int c = tid + 256 * i;
      int r = c >> 3, kk = (c & 7) << 3;
      *(short8*)&As[r][kk] = *(const short8*)&Ab[(m0 + r) * (long)lda + k0 + kk];
    }
    if (BT) {
#pragma unroll
      for (int i = 0; i < 2; i++) {
        int c = tid + 256 * i;
        int r = c >> 3, kk = (c & 7) << 3;
        *(short8*)&Bs[r][kk] = *(const short8*)&Bb[(n0 + r) * (long)ldb + k0 + kk];
      }
    } else {
#pragma unroll
      for (int i = 0; i < 2; i++) {
        int c = tid + 256 * i;
        int kk = c >> 3, nn = (c & 7) << 3;
        const u16* s = &Bb[(long)(k0 + kk) * ldb + n0 + nn];
#pragma unroll
        for (int j = 0; j < 8; j++) Bs[nn + j][kk] = s[j];
      }
    }
    __syncthreads();
#pragma unroll
    for (int kf = 0; kf < 2; kf++) {
      const int ko = kf * 32 + (lane >> 4) * 8;
      short8 a0 = *(const short8*)&As[wm * 32 + (lane & 15)][ko];
      short8 a1 = *(const short8*)&As[wm * 32 + 16 + (lane & 15)][ko];
      short8 b0 = *(const short8*)&Bs[wn * 32 + (lane & 15)][ko];
      short8 b1 = *(const short8*)&Bs[wn * 32 + 16 + (lane & 15)][ko];
      acc[0][0] = mfma16(a0, b0, acc[0][0]);
      acc[0][1] = mfma16(a0, b1, acc[0][1]);
      acc[1][0] = mfma16(a1, b0, acc[1][0]);
      acc[1][1] = mfma16(a1, b1, acc[1][1]);
    }
    __syncthreads();
  }
#pragma unroll
  for (int m = 0; m < 2; m++)
#pragma unroll
    for (int n = 0; n < 2; n++) {
#pragma unroll
      for (int r = 0; r < 4; r++) {
        long row = m0 + wm * 32 + m * 16 + (lane >> 4) * 4 + r;
        long col = n0 + wn * 32 + n * 16 + (lane & 15);
        float v = acc[m][n][r];
        if (BIAS) v += bias[col];
        if (DOTANH) v = tanhf(v);
        if (OBF) ((u16*)Cv)[(long)z * c_bs + row * ldc + col] = f2bf(v);
        else ((float*)Cv)[(long)z * c_bs + row * ldc + col] = v;
      }
    }
}

// ---------------- 128² bf16 MFMA GEMM, BT only, global_load_lds staging (m97 structure) ---------
// CAUSAL3: scores-only variant — 256x256 causal output per batch; the (kblk=1,qblk=0)
// tile is fully masked (never read by softmax), so launch 3 tiles/batch:
// id 0 -> (n0=0,m0=0), 1 -> (0,128), 2 -> (128,128).
template<bool OBF, bool DOTANH, bool BIAS, bool CAUSAL3>
__global__ __launch_bounds__(256) void gemm128_kernel(
    const u16* __restrict__ A, const u16* __restrict__ Bm, void* __restrict__ Cv,
    const float* __restrict__ bias,
    int K, int lda, int ldb, int ldc,
    long a_bs, long b_bs, long c_bs)
{
  __shared__ u16 As[128 * 64];   // linear [row][64], row stride 64 u16
  __shared__ u16 Bs[128 * 64];
  const int tid = threadIdx.x;
  long m0, n0;
  if (CAUSAL3) {
    int id = blockIdx.x;                    // 0..2
    m0 = (id > 0) ? 128 : 0;
    n0 = (id > 1) ? 128 : 0;
  } else {
    m0 = (long)blockIdx.y * 128;
    n0 = (long)blockIdx.x * 128;
  }
  const int z = blockIdx.z;
  const u16* Ab = A + (long)z * a_bs;
  const u16* Bb = Bm + (long)z * b_bs;
  const int lane = tid & 63, w = tid >> 6;
  const int wm = w >> 1, wn = w & 1;
  const int rr = tid >> 3, kk = (tid & 7) << 3;   // per-issue i: row = i*32 + rr
  f32x4 acc[4][4] = {};
  for (int k0 = 0; k0 < K; k0 += 64) {
#pragma unroll
    for (int i = 0; i < 4; i++) {
      gload_lds16(&Ab[(m0 + i * 32 + rr) * (long)lda + k0 + kk],
                  As + (i * 256 + (w << 6)) * 8);
      gload_lds16(&Bb[(n0 + i * 32 + rr) * (long)ldb + k0 + kk],
                  Bs + (i * 256 + (w << 6)) * 8);
    }
    __syncthreads();   // drains vmcnt(0): LDS tiles complete
#pragma unroll
    for (int kf = 0; kf < 2; kf++) {
      const int ko = kf * 32 + (lane >> 4) * 8;
      short8 a[4], b[4];
#pragma unroll
      for (int mi = 0; mi < 4; mi++)
        a[mi] = *(const short8*)&As[(wm * 64 + mi * 16 + (lane & 15)) * 64 + ko];
#pragma unroll
      for (int ni = 0; ni < 4; ni++)
        b[ni] = *(const short8*)&Bs[(wn * 64 + ni * 16 + (lane & 15)) * 64 + ko];
#pragma unroll
      for (int mi = 0; mi < 4; mi++)
#pragma unroll
        for (int ni = 0; ni < 4; ni++)
          acc[mi][ni] = mfma16(a[mi], b[ni], acc[mi][ni]);
    }
    __syncthreads();
  }
#pragma unroll
  for (int mi = 0; mi < 4; mi++)
#pragma unroll
    for (int ni = 0; ni < 4; ni++) {
#pragma unroll
      for (int r = 0; r < 4; r++) {
        long row = m0 + wm * 64 + mi * 16 + (lane >> 4) * 4 + r;
        long col = n0 + wn * 64 + ni * 16 + (lane & 15);
        float v = acc[mi][ni][r];
        if (BIAS) v += bias[col];
        if (DOTANH) v = tanhf(v);
        if (OBF) ((u16*)Cv)[(long)z * c_bs + row * ldc + col] = f2bf(v);
        else ((float*)Cv)[(long)z * c_bs + row * ldc + col] = v;
      }
    }
}

// ---------------- sentinel prefill (standalone, for LSTM2's refill) ----------------
__global__ void sentinel_kernel(u16* __restrict__ p) {
  long i = ((long)blockIdx.x * 256 + threadIdx.x) * 8;
  short v = (i < 8192) ? (short)0 : (short)SENT;
  short8 s = {v, v, v, v, v, v, v, v};
  *(short8*)&p[i] = s;
}

// ---------------- persistent LSTM: round-9 EXACT (proven 528 µs) ----------------
// 32 blocks x 256 threads; sentinel-tagged staged handoff; simple 4-chunk poll;
// coalesced publish/hout/xg (thread (b=tid>>4, jl=tid&15) owns (batch b, unit nb*16+jl)).
// MODE 0: write h into cat[:, 512:1024]. MODE 1: write h into h2 (ld 512).
template<int MODE>
__global__ __launch_bounds__(256) void lstm_kernel(
    const float* __restrict__ xw,   // [4096][2048] permuted, biases folded in
    const u16* __restrict__ Whh,    // [2048][512] permuted rows, bf16
    u16* __restrict__ Hseq,         // [257][16][512] sentinel-prefilled
    u16* __restrict__ hout)
{
  const int nb = blockIdx.x;
  const int tid = threadIdx.x;
  const int lane = tid & 63, w = tid >> 6;
  __shared__ u16 hs[16][520];       // staged h_{t-1}; +8 u16 pad keeps rows 16B-aligned
  __shared__ float gbuf[16][64];
  const int ncol0 = nb * 64 + w * 16;
  short8 bfrag[16];
  {
    const u16* wr = Whh + (long)(ncol0 + (lane & 15)) * 512 + ((lane >> 4) * 8);
#pragma unroll
    for (int kf = 0; kf < 16; kf++) bfrag[kf] = *(const short8*)&wr[kf * 32];
  }
  const int b = tid >> 4, jl = tid & 15;
  const int jglob = nb * 16 + jl;
  int cc[4];                        // 16B-chunk ids, rotated per block
#pragma unroll
  for (int i = 0; i < 4; i++) cc[i] = (tid + i * 256 + nb * 32) & 1023;
  float c = 0.f;
  float4 xg = *(const float4*)&xw[((long)b * LL) * GG + nb * 64 + jl * 4];
  for (int t = 0; t < LL; t++) {
    // ---- poll-stage h_{t-1}: re-issue own 4 chunks until sentinel-free ----
    const u16* Hin = Hseq + (long)t * 8192;
    short8 sv[4];
    int bad;
    do {
#pragma unroll
      for (int i = 0; i < 4; i++)
        asm volatile("global_load_dwordx4 %0, %1, off sc1"
                     : "=v"(sv[i]) : "v"(Hin + (cc[i] >> 6) * 512 + (cc[i] & 63) * 8));
      asm volatile("s_waitcnt vmcnt(0)" ::: "memory");
      __builtin_amdgcn_sched_barrier(0);   // rule #18: nothing crosses the waitcnt
      bad = 0;
#pragma unroll
      for (int i = 0; i < 4; i++) {
        const int* dv = (const int*)&sv[i];
#pragma unroll
        for (int d = 0; d < 4; d++) bad |= ((dv[d] & 0xFFFF) == SENT);
      }
    } while (__any(bad != 0));
    __builtin_amdgcn_sched_barrier(0);
#pragma unroll
    for (int i = 0; i < 4; i++)
      *(short8*)&hs[cc[i] >> 6][(cc[i] & 63) * 8] = sv[i];
    __syncthreads();                 // barrier 1: hs staged
    // ---- MFMA from LDS fragments ----
    f32x4 acc0 = {}, acc1 = {};
#pragma unroll
    for (int kf = 0; kf < 8; kf++) {
      short8 a0 = *(const short8*)&hs[lane & 15][(lane >> 4) * 8 + (2 * kf) * 32];
      short8 a1 = *(const short8*)&hs[lane & 15][(lane >> 4) * 8 + (2 * kf + 1) * 32];
      acc0 = mfma16(a0, bfrag[2 * kf], acc0);
      acc1 = mfma16(a1, bfrag[2 * kf + 1], acc1);
    }
    f32x4 acc = acc0 + acc1;
#pragma unroll
    for (int r = 0; r < 4; r++)
      gbuf[(lane >> 4) * 4 + r][w * 16 + (lane & 15)] = acc[r];
    __syncthreads();                 // barrier 2: gbuf ready (also fences hs reads)
    float gi = sigmoidf_(gbuf[b][jl * 4 + 0] + xg.x);
    float gf = sigmoidf_(gbuf[b][jl * 4 + 1] + xg.y);
    float gg = tanhf(gbuf[b][jl * 4 + 2] + xg.z);
    float go = sigmoidf_(gbuf[b][jl * 4 + 3] + xg.w);
    c = gf * c + gi * gg;
    float h = go * tanhf(c);
    u16 hb = f2bf(h);
    // ---- publish h_t: pack pairs, one atomic dword sc1 store per even-jl thread ----
    unsigned hi16 = (unsigned)__shfl_down((int)(unsigned)hb, 1);
    if ((jl & 1) == 0) {
      int pk = (int)((unsigned)hb | (hi16 << 16));
      st_b32_dev((int*)&Hseq[((long)t + 1) * 8192 + b * 512 + jglob], pk);
    }
    if (MODE == 0) hout[((long)b * LL + t) * 1024 + 512 + jglob] = hb;
    else           hout[((long)b * LL + t) * 512 + jglob] = hb;
    // next step's gate slice (plain load; retired by the next poll's vmcnt(0))
    if (t + 1 < LL)
      xg = *(const float4*)&xw[((long)b * LL + (t + 1)) * GG + nb * 64 + jl * 4];
  }
}

// ---------------- fused prep: all independent elementwise prework in ONE launch ----------------
__global__ __launch_bounds__(256) void prep_kernel(
    const float* __restrict__ l1_Wih, const float* __restrict__ l1_Whh,
    const float* __restrict__ dc_Wih, const float* __restrict__ dc_Whh,
    const float* __restrict__ l1_bih, const float* __restrict__ l1_bhh,
    const float* __restrict__ dc_bih, const float* __restrict__ dc_bhh,
    const float* __restrict__ Wout,  const float* __restrict__ fc2_w,
    const int*   __restrict__ y,     const float* __restrict__ emb,
    const float* __restrict__ x,     const float* __restrict__ fc1_w,
    const float* __restrict__ fc1_b,
    u16* wih1, u16* whh1, u16* wih2, u16* whh2,
    float* b1p, float* b2p, u16* woutb, u16* fc2wb,
    u16* seqb, u16* Hseq, float* feat)
{
  const int bid = blockIdx.x;
  const int tid = threadIdx.x;
  if (bid < 8192) {                       // 4 weight permute+converts
    int grp = bid >> 11, n = bid & 2047;
    const float* s; u16* d; int ldk;
    if (grp == 0)      { s = l1_Wih; d = wih1; ldk = EMBD; }
    else if (grp == 1) { s = l1_Whh; d = whh1; ldk = DEC; }
    else if (grp == 2) { s = dc_Wih; d = wih2; ldk = DEC; }
    else               { s = dc_Whh; d = whh2; ldk = DEC; }
    int r = (n & 3) * DEC + (n >> 2);
    for (int k = tid; k < ldk; k += 256)
      d[(long)n * ldk + k] = f2bf(s[(long)r * ldk + k]);
  } else if (bid < 8208) {                // bias folds
    int idx = bid - 8192;
    int n = (idx & 7) * 256 + tid;
    int r = (n & 3) * DEC + (n >> 2);
    if (idx < 8) b1p[n] = l1_bih[r] + l1_bhh[r];
    else         b2p[n] = dc_bih[r] + dc_bhh[r];
  } else if (bid < 8720) {                // woutb cvt
    long i = ((long)(bid - 8208) * 256 + tid) * 4;
    float4 v = *(const float4*)&Wout[i];
    u16x4 o = {f2bf(v.x), f2bf(v.y), f2bf(v.z), f2bf(v.w)};
    *(u16x4*)&woutb[i] = o;
  } else if (bid < 24720) {               // fc2wb cvt
    long i = ((long)(bid - 8720) * 256 + tid) * 4;
    float4 v = *(const float4*)&fc2_w[i];
    u16x4 o = {f2bf(v.x), f2bf(v.y), f2bf(v.z), f2bf(v.w)};
    *(u16x4*)&fc2wb[i] = o;
  } else if (bid < 28800) {               // embed
    int idx = bid - 24720;
    int t = idx % TY, bb = idx / TY;
    int tok = y[bb * TY + t];
    seqb[((long)bb * LL + 1 + t) * EMBD + tid] = f2bf(emb[(long)tok * EMBD + tid]);
  } else if (bid < 29828) {               // sentinel prefill
    long i = ((long)(bid - 28800) * 256 + tid) * 8;
    short v = (i < 8192) ? (short)0 : (short)SENT;
    short8 s = {v, v, v, v, v, v, v, v};
    *(short8*)&Hseq[i] = s;
  } else {                                // fc1
    __shared__ float xs[ENC];
    int bb = bid - 29828;
    for (int k = tid; k < ENC; k += 256) xs[k] = x[bb * ENC + k];
    __syncthreads();
    float s = fc1_b[tid];
    const float* wr = fc1_w + (long)tid * ENC;
    for (int k = 0; k < ENC; k += 4) {
      float4 wv = *(const float4*)&wr[k];
      s += xs[k] * wv.x + xs[k + 1] * wv.y + xs[k + 2] * wv.z + xs[k + 3] * wv.w;
    }
    feat[bb * EMBD + tid] = s;
  }
}

__global__ void bn_embed0_kernel(const float* __restrict__ feat, const float* __restrict__ g,
                                 const float* __restrict__ bb, u16* __restrict__ seq) {
  int j = threadIdx.x;  // 256 features, 1 block
  float mu = 0.f, m2 = 0.f;
  for (int i = 0; i < BB; i++) { float v = feat[i * EMBD + j]; mu += v; m2 += v * v; }
  mu *= (1.f / BB);
  float var = m2 * (1.f / BB) - mu * mu;
  float sc = g[j] * rsqrtf(var + 1e-5f);
  float sh = bb[j];
  for (int i = 0; i < BB; i++) {
    float v = (feat[i * EMBD + j] - mu) * sc + sh;
    seq[((long)i * LL) * EMBD + j] = f2bf(v);
  }
}

__global__ __launch_bounds__(256) void softmax_kernel(const float* __restrict__ sc,
                                                      u16* __restrict__ wsm) {
  int row = blockIdx.x;
  int q = row & (LL - 1);
  int k = threadIdx.x;
  __shared__ float red[8];
  float v = (k <= q) ? sc[(long)row * LL + k] : -3.4e38f;
  float m = v;
#pragma unroll
  for (int o = 32; o > 0; o >>= 1) m = fmaxf(m, __shfl_xor(m, o));
  if ((k & 63) == 0) red[k >> 6] = m;
  __syncthreads();
  m = fmaxf(fmaxf(red[0], red[1]), fmaxf(red[2], red[3]));
  float e = (k <= q) ? expf(v - m) : 0.f;
  float s = e;
#pragma unroll
  for (int o = 32; o > 0; o >>= 1) s += __shfl_xor(s, o);
  if ((k & 63) == 0) red[4 + (k >> 6)] = s;
  __syncthreads();
  s = red[4] + red[5] + red[6] + red[7];
  wsm[(long)row * LL + k] = f2bf(e / s);
}

extern "C" void kernel_launch(void* const* d_in, const int* in_sizes, int n_in,
                              void* d_out, int out_size, void* d_ws, size_t ws_size,
                              hipStream_t stream) {
  const float* x      = (const float*)d_in[0];
  const int*   y      = (const int*)d_in[1];
  const float* fc1_w  = (const float*)d_in[2];
  const float* fc1_b  = (const float*)d_in[3];
  const float* bn_g   = (const float*)d_in[4];
  const float* bn_b   = (const float*)d_in[5];
  const float* emb    = (const float*)d_in[6];
  const float* l1_Wih = (const float*)d_in[7];
  const float* l1_Whh = (const float*)d_in[8];
  const float* l1_bih = (const float*)d_in[9];
  const float* l1_bhh = (const float*)d_in[10];
  const float* Wout   = (const float*)d_in[11];
  const float* dc_Wih = (const float*)d_in[12];
  const float* dc_Whh = (const float*)d_in[13];
  const float* dc_bih = (const float*)d_in[14];
  const float* dc_bhh = (const float*)d_in[15];
  const float* fc2_w  = (const float*)d_in[16];
  const float* fc2_b  = (const float*)d_in[17];
  float* out = (float*)d_out;

  char* ws = (char*)d_ws;
  float* xw     = (float*)(ws + 0);          // 4096*2048 f32 (reused for both LSTMs)
  u16*   seqb   = (u16*)(ws + 33554432);     // 4096*256 bf16
  u16*   cat    = (u16*)(ws + 35651584);     // 4096*1024 bf16  [mix | h1]
  float* scores = (float*)(ws + 44040192);   // 16*256*256 f32
  u16*   Hseq   = (u16*)(ws + 44040192);     // 257*16*512 bf16 — aliases scores (disjoint lifetime)
  u16*   wsm    = (u16*)(ws + 48234496);     // 16*256*256 bf16 (head overlaps Hseq tail, disjoint lifetime)
  u16*   attnb  = (u16*)(ws + 50331648);     // 4096*512 bf16
  u16*   h2b    = (u16*)(ws + 54525952);     // 4096*512 bf16
  u16*   wih1   = (u16*)(ws + 58720256);     // 2048*256
  u16*   whh1   = (u16*)(ws + 59768832);     // 2048*512
  u16*   wih2   = (u16*)(ws + 61865984);     // 2048*512
  u16*   whh2   = (u16*)(ws + 63963136);     // 2048*512
  u16*   woutb  = (u16*)(ws + 66060288);     // 512*1024
  u16*   fc2wb  = (u16*)(ws + 67108864);     // 32000*512
  float* b1p    = (float*)(ws + 99876864);   // 2048
  float* b2p    = (float*)(ws + 99885056);   // 2048
  float* feat   = (float*)(ws + 99893248);   // 16*256

  // ---- fused prep: weights/biases/embed/sentinel/fc1 in one launch ----
  prep_kernel<<<29844, 256, 0, stream>>>(
      l1_Wih, l1_Whh, dc_Wih, dc_Whh, l1_bih, l1_bhh, dc_bih, dc_bhh,
      Wout, fc2_w, y, emb, x, fc1_w, fc1_b,
      wih1, whh1, wih2, whh2, b1p, b2p, woutb, fc2wb, seqb, Hseq, feat);
  bn_embed0_kernel<<<1, 256, 0, stream>>>(feat, bn_g, bn_b, seqb);

  // xw1 = seq @ l1_Wih^T + (bih+bhh)   M=4096 N=2048 K=256
  gemm128_kernel<false, false, true, false><<<dim3(GG / 128, M4 / 128, 1), 256, 0, stream>>>(
      seqb, wih1, xw, b1p, EMBD, EMBD, EMBD, GG, 0, 0, 0);
  // LSTM1 -> h1 into cat[:,512:1024]
  lstm_kernel<0><<<32, 256, 0, stream>>>(xw, whh1, Hseq, cat);
  // scores[b] = h1 @ h1^T   (per batch) — causal: skip the fully-masked (k>q) tile
  gemm128_kernel<false, false, false, true><<<dim3(3, 1, BB), 256, 0, stream>>>(
      cat + 512, cat + 512, scores, nullptr, DEC, 1024, 1024, LL,
      (long)LL * 1024, (long)LL * 1024, (long)LL * LL);
  softmax_kernel<<<M4, 256, 0, stream>>>(scores, wsm);
  // mix[b] = wsm @ h1 (NN) -> cat[:,0:512] bf16   (64² kernel: NN path)
  gemm_kernel<false, true, false, false><<<dim3(DEC / 64, LL / 64, BB), 256, 0, stream>>>(
      wsm, cat + 512, cat, nullptr, LL, LL, 1024, 1024,
      (long)LL * LL, (long)LL * 1024, (long)LL * 1024);
  // attn = tanh(cat @ Wout^T)   M=4096 N=512 K=1024
  gemm128_kernel<true, true, false, false><<<dim3(DEC / 128, M4 / 128, 1), 256, 0, stream>>>(
      cat, woutb, attnb, nullptr, 1024, 1024, 1024, DEC, 0, 0, 0);
  // xw2 = attn @ dc_Wih^T + (bih+bhh)   M=4096 N=2048 K=512
  gemm128_kernel<false, false, true, false><<<dim3(GG / 128, M4 / 128, 1), 256, 0, stream>>>(
      attnb, wih2, xw, b2p, DEC, DEC, DEC, GG, 0, 0, 0);
  // LSTM2 -> h2 (scores/wsm head dead again -> re-sentinel Hseq)
  sentinel_kernel<<<1028, 256, 0, stream>>>(Hseq);
  lstm_kernel<1><<<32, 256, 0, stream>>>(xw, whh2, Hseq, h2b);
  // out = h2 @ fc2_w^T + fc2_b   M=4096 N=32000 K=512  (default order — round-13 proven)
  gemm128_kernel<false, false, true, false><<<dim3(VV / 128, M4 / 128, 1), 256, 0, stream>>>(
      h2b, fc2wb, out, fc2_b, DEC, DEC, DEC, VV, 0, 0, 0);
}